// Round 4
// baseline (240.568 us; speedup 1.0000x reference)
//
#include <hip/hip_runtime.h>
#include <math.h>

namespace {
constexpr int Tn = 128, Bn = 16, An = 32, OBS = 256, Kh = 3, NACT = 9, HID = 32;
constexpr int TBA = Tn * Bn * An;   // 65536 rows through the MLP
constexpr int BA  = Bn * An;        // 512 LSTM sequences
constexpr int OUT_LP  = TBA * Kh;         // 196608: logprobs start
constexpr int OUT_ENT = TBA * Kh + TBA;   // 262144: entropies start

typedef _Float16 half4v __attribute__((ext_vector_type(4)));
typedef _Float16 half8v __attribute__((ext_vector_type(8)));
typedef float    f32x4  __attribute__((ext_vector_type(4)));
}

__device__ __forceinline__ float fast_sig(float x) {
  return __builtin_amdgcn_rcpf(1.f + __expf(-x));
}
__device__ __forceinline__ float fast_tanh(float x) {
  float xc = fminf(fmaxf(x, -10.f), 10.f);      // e^20 safe, tanh saturated
  float e = __expf(2.f * xc);
  return (e - 1.f) * __builtin_amdgcn_rcpf(e + 1.f);
}

// ---------------------------------------------------------------------------
// Fused MLP trunk + LSTM input projection, f16 MFMA (fp32 accumulate):
//   z = tanh(tanh(x@W1'+b1)@W2'+b2)@W3'+b3 ; G1 = z@Wih' + bih + bhh
// ---------------------------------------------------------------------------
template<int ROWS, int WSTR>
__device__ __forceinline__ void stage_w16(const float* __restrict__ Wg, int kofs,
                                          _Float16* __restrict__ wt, int tid)
{
#pragma unroll
  for (int it = 0; it < ROWS/16; ++it) {
    int idx = tid + it*256;
    int o = idx >> 4, k4 = idx & 15;
    float4 v = *(const float4*)&Wg[(size_t)o*WSTR + kofs + k4*4];
    half4v h = { (_Float16)v.x, (_Float16)v.y, (_Float16)v.z, (_Float16)v.w };
    *(half4v*)&wt[o*72 + k4*4] = h;
  }
}

template<int NOC, int XSTR>
__device__ __forceinline__ void mfma_slab(const _Float16* __restrict__ xsrc,
                                          const _Float16* __restrict__ wt,
                                          int rA, int ln, int quad, f32x4 acc[8])
{
#pragma unroll
  for (int kc = 0; kc < 2; ++kc) {
    half8v a = *(const half8v*)&xsrc[rA*XSTR + kc*32 + quad*8];
#pragma unroll
    for (int oc = 0; oc < NOC; ++oc) {
      half8v b = *(const half8v*)&wt[(oc*16 + ln)*72 + kc*32 + quad*8];
      acc[oc] = __builtin_amdgcn_mfma_f32_16x16x32_f16(a, b, acc[oc], 0, 0, 0);
    }
  }
}

__global__ __launch_bounds__(256) void mlp_kernel(
    const float* __restrict__ x,
    const float* __restrict__ W1, const float* __restrict__ b1,
    const float* __restrict__ W2, const float* __restrict__ b2,
    const float* __restrict__ W3, const float* __restrict__ b3,
    const float* __restrict__ Wih, const float* __restrict__ bih,
    const float* __restrict__ bhh, float* __restrict__ G1)
{
  __shared__ __align__(16) _Float16 xs[64*72];    // x k-slab; reused for z
  __shared__ __align__(16) _Float16 wt[128*72];   // weight k-slab
  __shared__ __align__(16) _Float16 act[64*136];  // activations (reused in place)
  const int tid  = threadIdx.x;
  const int w    = tid >> 6;
  const int lane = tid & 63;
  const int ln   = lane & 15;
  const int quad = lane >> 4;
  const int rA   = 16*w + ln;
  const int r0   = 16*w + quad*4;
  const int R0   = blockIdx.x * 64;
  f32x4 acc[8];

  // ---- layer 1: 256 -> 128, tanh (4 k-slabs of 64) ----
#pragma unroll
  for (int oc = 0; oc < 8; ++oc) acc[oc] = (f32x4)0.f;
  for (int kt = 0; kt < 4; ++kt) {
#pragma unroll
    for (int it = 0; it < 4; ++it) {
      int idx = tid + it*256;
      int r = idx >> 4, k4 = idx & 15;
      float4 v = *(const float4*)&x[(size_t)(R0 + r)*OBS + kt*64 + k4*4];
      half4v h = { (_Float16)v.x, (_Float16)v.y, (_Float16)v.z, (_Float16)v.w };
      *(half4v*)&xs[r*72 + k4*4] = h;
    }
    stage_w16<128, 256>(W1, kt*64, wt, tid);
    __syncthreads();
    mfma_slab<8, 72>(xs, wt, rA, ln, quad, acc);
    __syncthreads();
  }
#pragma unroll
  for (int oc = 0; oc < 8; ++oc) {
    int o = oc*16 + ln;
    float bv = b1[o];
#pragma unroll
    for (int r = 0; r < 4; ++r)
      act[(r0 + r)*136 + o] = (_Float16)tanhf(acc[oc][r] + bv);
  }

  // ---- layer 2: 128 -> 128, tanh ----
#pragma unroll
  for (int oc = 0; oc < 8; ++oc) acc[oc] = (f32x4)0.f;
  for (int kt = 0; kt < 2; ++kt) {
    stage_w16<128, 128>(W2, kt*64, wt, tid);
    __syncthreads();
    mfma_slab<8, 136>(act + kt*64, wt, rA, ln, quad, acc);
    __syncthreads();
  }
#pragma unroll
  for (int oc = 0; oc < 8; ++oc) {
    int o = oc*16 + ln;
    float bv = b2[o];
#pragma unroll
    for (int r = 0; r < 4; ++r)
      act[(r0 + r)*136 + o] = (_Float16)tanhf(acc[oc][r] + bv);
  }

  // ---- layer 3: 128 -> 64, linear -> z into xs buffer ----
#pragma unroll
  for (int oc = 0; oc < 4; ++oc) acc[oc] = (f32x4)0.f;
  for (int kt = 0; kt < 2; ++kt) {
    stage_w16<64, 128>(W3, kt*64, wt, tid);
    __syncthreads();
    mfma_slab<4, 136>(act + kt*64, wt, rA, ln, quad, acc);
    __syncthreads();
  }
#pragma unroll
  for (int oc = 0; oc < 4; ++oc) {
    int o = oc*16 + ln;
    float bv = b3[o];
#pragma unroll
    for (int r = 0; r < 4; ++r)
      xs[(r0 + r)*72 + o] = (_Float16)(acc[oc][r] + bv);
  }

  // ---- layer 4: z(64) -> 128 gate inputs: z@Wih' + bih + bhh ----
#pragma unroll
  for (int oc = 0; oc < 8; ++oc) acc[oc] = (f32x4)0.f;
  stage_w16<128, 64>(Wih, 0, wt, tid);
  __syncthreads();
  mfma_slab<8, 72>(xs, wt, rA, ln, quad, acc);
#pragma unroll
  for (int oc = 0; oc < 8; ++oc) {
    int o = oc*16 + ln;
    float badd = bih[o] + bhh[o];
#pragma unroll
    for (int r = 0; r < 4; ++r)
      G1[(size_t)(R0 + r0 + r)*128 + o] = acc[oc][r] + badd;
  }
}

// ---------------------------------------------------------------------------
// LSTM scan v3: 1 row per 64-lane wave, 512 blocks.
// Lane L computes gates L and L+64. u = L&31: lane u has i_u,g_u; lane u+32
// has f_u,o_u -> shfl_xor(32) pairs them for the c/h update (lanes<32).
// v3: depth-2 register prefetch of G1 (covers ~900cyc HBM latency with two
// ~550cyc iterations of slack) + 4-way split accumulators (dep chain
// 32 FMA -> 8 FMA + 2 add).
// ---------------------------------------------------------------------------
__global__ __launch_bounds__(64) void lstm_kernel(
    const float* __restrict__ G1, const float* __restrict__ Whh,
    const int* __restrict__ done, const float* __restrict__ h0,
    const float* __restrict__ c0, float* __restrict__ Y)
{
  __shared__ __align__(16) float hs[32];
  __shared__ float md[Tn];
  const int lane = threadIdx.x;        // 0..63
  const int u = lane & 31;
  const int row = blockIdx.x;          // 0..511
  const int b = row >> 5;

  float4 wlo[8], whi[8];               // Whh rows for gates (lane), (lane+64)
#pragma unroll
  for (int k4 = 0; k4 < 8; ++k4) {
    wlo[k4] = *(const float4*)&Whh[lane*HID + k4*4];
    whi[k4] = *(const float4*)&Whh[(64 + lane)*HID + k4*4];
  }
  md[lane]      = 1.f - (float)done[lane*Bn + b];
  md[lane + 64] = 1.f - (float)done[(lane + 64)*Bn + b];
  float h = h0[row*HID + u];
  float c = c0[row*HID + u];
  __syncthreads();

  // depth-2 prefetch pipeline: A = step t, B = step t+1
  const size_t rbase = (size_t)row*128;
  float glA = G1[rbase + lane],               ghA = G1[rbase + 64 + lane];
  float glB = G1[(size_t)BA*128 + rbase + lane],
        ghB = G1[(size_t)BA*128 + rbase + 64 + lane];
  float mA = md[0], mB = md[1];

  for (int t = 0; t < Tn; ++t) {
    float gl = glA, gh = ghA, m = mA;
    glA = glB; ghA = ghB; mA = mB;
    int tp = t + 2; tp = (tp < Tn) ? tp : (Tn - 1);   // clamped, branch-free
    const float* gq = G1 + ((size_t)tp*BA + row)*128;
    glB = gq[lane]; ghB = gq[64 + lane];
    mB = md[tp];

    h *= m; c *= m;
    if (lane < 32) hs[u] = h;
    __syncthreads();                   // single wave: cheap

    float pl[4] = { gl, 0.f, 0.f, 0.f };
    float ph[4] = { gh, 0.f, 0.f, 0.f };
#pragma unroll
    for (int k4 = 0; k4 < 8; ++k4) {
      float4 hv = *(const float4*)&hs[k4*4];   // broadcast read, conflict-free
      int p = k4 & 3;
      pl[p] = fmaf(wlo[k4].x, hv.x, pl[p]); pl[p] = fmaf(wlo[k4].y, hv.y, pl[p]);
      pl[p] = fmaf(wlo[k4].z, hv.z, pl[p]); pl[p] = fmaf(wlo[k4].w, hv.w, pl[p]);
      ph[p] = fmaf(whi[k4].x, hv.x, ph[p]); ph[p] = fmaf(whi[k4].y, hv.y, ph[p]);
      ph[p] = fmaf(whi[k4].z, hv.z, ph[p]); ph[p] = fmaf(whi[k4].w, hv.w, ph[p]);
    }
    gl = (pl[0] + pl[1]) + (pl[2] + pl[3]);
    gh = (ph[0] + ph[1]) + (ph[2] + ph[3]);

    float slo = fast_sig(gl);          // lanes<32: i_u ; lanes>=32: f_u
    float th  = fast_tanh(gh);
    float sh  = fast_sig(gh);
    float ahi = (lane < 32) ? th : sh; // lanes<32: g_u ; lanes>=32: o_u
    float fv = __shfl_xor(slo, 32);    // lanes<32 receive f_u
    float ov = __shfl_xor(ahi, 32);    // lanes<32 receive o_u
    c = fmaf(fv, c, slo * ahi);        // valid on lanes<32
    h = ov * fast_tanh(c);
    if (lane < 32) Y[((size_t)t*BA + row)*HID + u] = h;
  }
}

// ---------------------------------------------------------------------------
// Heads: per row, 27 logits (3 heads x 9), log-softmax, entropy, gather,
// product of chosen log-probs. One thread per row; y staged in LDS (+1 pad).
// ---------------------------------------------------------------------------
__global__ __launch_bounds__(256) void head_kernel(
    const float* __restrict__ Y, const float* __restrict__ Wh,
    const float* __restrict__ bh, const int* __restrict__ actions,
    float* __restrict__ out)
{
  __shared__ float ys[256*33];
  __shared__ __align__(16) float whs[27*32];
  __shared__ float bhs[32];
  const int tid = threadIdx.x;
  const int R0 = blockIdx.x * 256;
  for (int i = tid; i < 27*32; i += 256) whs[i] = Wh[i];
  if (tid < 27) bhs[tid] = bh[tid];
#pragma unroll
  for (int it = 0; it < 8; ++it) {
    int idx = tid + it*256;
    int r = idx >> 3, f4 = idx & 7;
    float4 v = *(const float4*)&Y[(size_t)(R0 + r)*32 + f4*4];
    ys[r*33 + f4*4 + 0] = v.x;
    ys[r*33 + f4*4 + 1] = v.y;
    ys[r*33 + f4*4 + 2] = v.z;
    ys[r*33 + f4*4 + 3] = v.w;
  }
  __syncthreads();
  float yv[32];
#pragma unroll
  for (int k = 0; k < 32; ++k) yv[k] = ys[tid*33 + k];
  float l[27];
#pragma unroll
  for (int m = 0; m < 27; ++m) {
    float a = bhs[m];
#pragma unroll
    for (int k4 = 0; k4 < 8; ++k4) {
      float4 w4 = *(const float4*)&whs[m*32 + k4*4];   // uniform -> broadcast
      a = fmaf(yv[k4*4+0], w4.x, a);
      a = fmaf(yv[k4*4+1], w4.y, a);
      a = fmaf(yv[k4*4+2], w4.z, a);
      a = fmaf(yv[k4*4+3], w4.w, a);
    }
    l[m] = a;
  }
  const int row = R0 + tid;
  float logprob = 1.0f;
#pragma unroll
  for (int kk = 0; kk < 3; ++kk) {
    float mx = l[kk*9];
#pragma unroll
    for (int n = 1; n < 9; ++n) mx = fmaxf(mx, l[kk*9+n]);
    float s = 0.f;
#pragma unroll
    for (int n = 0; n < 9; ++n) s += __expf(l[kk*9+n] - mx);
    float lse = mx + __logf(s);
    float ent = 0.f;
#pragma unroll
    for (int n = 0; n < 9; ++n) {
      float lp = l[kk*9+n] - lse;
      ent -= __expf(lp) * lp;
    }
    int a = actions[row*3 + kk];
    float alp = 0.f;
#pragma unroll
    for (int n = 0; n < 9; ++n) alp = (a == n) ? (l[kk*9+n] - lse) : alp;
    logprob *= alp;
    out[row*3 + kk] = (float)a;          // actions echoed as float
    out[OUT_ENT + row*3 + kk] = ent;
  }
  out[OUT_LP + row] = logprob;
}

extern "C" void kernel_launch(void* const* d_in, const int* in_sizes, int n_in,
                              void* d_out, int out_size, void* d_ws, size_t ws_size,
                              hipStream_t stream)
{
  const float* x       = (const float*)d_in[0];
  const int*   done    = (const int*)  d_in[1];
  const int*   actions = (const int*)  d_in[2];
  const float* W1  = (const float*)d_in[3];
  const float* b1  = (const float*)d_in[4];
  const float* W2  = (const float*)d_in[5];
  const float* b2  = (const float*)d_in[6];
  const float* W3  = (const float*)d_in[7];
  const float* b3  = (const float*)d_in[8];
  const float* Wih = (const float*)d_in[9];
  const float* Whh = (const float*)d_in[10];
  const float* bih = (const float*)d_in[11];
  const float* bhh = (const float*)d_in[12];
  const float* Wh  = (const float*)d_in[13];
  const float* bh  = (const float*)d_in[14];
  const float* h0  = (const float*)d_in[15];
  const float* c0  = (const float*)d_in[16];
  float* out = (float*)d_out;

  float* G1 = (float*)d_ws;                    // [65536][128] = 33.5 MB
  float* Y  = G1 + (size_t)TBA * 128;          // [65536][32]  =  8.4 MB

  mlp_kernel<<<TBA/64, 256, 0, stream>>>(x, W1, b1, W2, b2, W3, b3,
                                         Wih, bih, bhh, G1);
  lstm_kernel<<<BA, 64, 0, stream>>>(G1, Whh, done, h0, c0, Y);
  head_kernel<<<TBA/256, 256, 0, stream>>>(Y, Wh, bh, actions, out);
}

// Round 5
// 220.098 us; speedup vs baseline: 1.0930x; 1.0930x over previous
//
#include <hip/hip_runtime.h>
#include <math.h>

namespace {
constexpr int Tn = 128, Bn = 16, An = 32, OBS = 256, Kh = 3, NACT = 9, HID = 32;
constexpr int TBA = Tn * Bn * An;   // 65536 rows through the MLP
constexpr int BA  = Bn * An;        // 512 LSTM sequences
constexpr int OUT_LP  = TBA * Kh;         // 196608: logprobs start
constexpr int OUT_ENT = TBA * Kh + TBA;   // 262144: entropies start

// fp16 weight pack offsets (elements)
constexpr int W1_OFF  = 0;       // 128x256
constexpr int W2_OFF  = 32768;   // 128x128
constexpr int W3_OFF  = 49152;   // 64x128
constexpr int WIH_OFF = 57344;   // 128x64
constexpr int W16_TOT = 65536;

typedef _Float16 half4v __attribute__((ext_vector_type(4)));
typedef _Float16 half8v __attribute__((ext_vector_type(8)));
typedef float    f32x4  __attribute__((ext_vector_type(4)));
}

__device__ __forceinline__ float fast_sig(float x) {
  return __builtin_amdgcn_rcpf(1.f + __expf(-x));
}
__device__ __forceinline__ float fast_tanh(float x) {
  float xc = fminf(fmaxf(x, -10.f), 10.f);      // e^20 safe, tanh saturated
  float e = __expf(2.f * xc);
  return (e - 1.f) * __builtin_amdgcn_rcpf(e + 1.f);
}
__device__ __forceinline__ float bcast_lane(float v, int k) {
  return __uint_as_float(__builtin_amdgcn_readlane(__float_as_uint(v), k));
}

// ---------------------------------------------------------------------------
// Weight pre-conversion: all four matrices fp32 -> fp16 once per call.
// ---------------------------------------------------------------------------
__global__ __launch_bounds__(256) void cvtw_kernel(
    const float* __restrict__ W1, const float* __restrict__ W2,
    const float* __restrict__ W3, const float* __restrict__ Wih,
    _Float16* __restrict__ w16)
{
  int i = blockIdx.x * 256 + threadIdx.x;       // 0..65535
  float v;
  if (i < W2_OFF)       v = W1[i];
  else if (i < W3_OFF)  v = W2[i - W2_OFF];
  else if (i < WIH_OFF) v = W3[i - W3_OFF];
  else                  v = Wih[i - WIH_OFF];
  w16[i] = (_Float16)v;
}

// ---------------------------------------------------------------------------
// Fused MLP trunk + LSTM input projection, f16 MFMA (fp32 accumulate):
//   z = tanh(tanh(x@W1'+b1)@W2'+b2)@W3'+b3 ; G1 = z@Wih' + bih + bhh
// Weights arrive pre-converted fp16 -> staging is half8 load + ds_write_b128.
// LDS row stride 72 halfs (144 B = 9 granules): granule bank-quad rotates by
// 1 per row -> both b128 writes and A/B-frag b128 reads are sweep-uniform.
// ---------------------------------------------------------------------------
template<int ROWS, int WSTR>
__device__ __forceinline__ void stage_wh(const _Float16* __restrict__ Wg, int kofs,
                                         _Float16* __restrict__ wt, int tid)
{
#pragma unroll
  for (int it = 0; it < ROWS/32; ++it) {
    int idx = tid + it*256;
    int o = idx >> 3, g8 = idx & 7;
    *(half8v*)&wt[o*72 + g8*8] =
        *(const half8v*)&Wg[(size_t)o*WSTR + kofs + g8*8];
  }
}

template<int NOC, int XSTR>
__device__ __forceinline__ void mfma_slab(const _Float16* __restrict__ xsrc,
                                          const _Float16* __restrict__ wt,
                                          int rA, int ln, int quad, f32x4 acc[8])
{
#pragma unroll
  for (int kc = 0; kc < 2; ++kc) {
    half8v a = *(const half8v*)&xsrc[rA*XSTR + kc*32 + quad*8];
#pragma unroll
    for (int oc = 0; oc < NOC; ++oc) {
      half8v b = *(const half8v*)&wt[(oc*16 + ln)*72 + kc*32 + quad*8];
      acc[oc] = __builtin_amdgcn_mfma_f32_16x16x32_f16(a, b, acc[oc], 0, 0, 0);
    }
  }
}

__global__ __launch_bounds__(256) void mlp_kernel(
    const float* __restrict__ x, const _Float16* __restrict__ w16,
    const float* __restrict__ b1, const float* __restrict__ b2,
    const float* __restrict__ b3, const float* __restrict__ bih,
    const float* __restrict__ bhh, float* __restrict__ G1)
{
  __shared__ __align__(16) _Float16 xs[64*72];    // x k-slab; reused for z
  __shared__ __align__(16) _Float16 wt[128*72];   // weight k-slab
  __shared__ __align__(16) _Float16 act[64*136];  // activations (reused in place)
  const _Float16* W1h  = w16 + W1_OFF;
  const _Float16* W2h  = w16 + W2_OFF;
  const _Float16* W3h  = w16 + W3_OFF;
  const _Float16* Wihh = w16 + WIH_OFF;
  const int tid  = threadIdx.x;
  const int w    = tid >> 6;
  const int lane = tid & 63;
  const int ln   = lane & 15;
  const int quad = lane >> 4;
  const int rA   = 16*w + ln;
  const int r0   = 16*w + quad*4;
  const int R0   = blockIdx.x * 64;
  f32x4 acc[8];

  // ---- layer 1: 256 -> 128, tanh (4 k-slabs of 64) ----
#pragma unroll
  for (int oc = 0; oc < 8; ++oc) acc[oc] = (f32x4)0.f;
  for (int kt = 0; kt < 4; ++kt) {
#pragma unroll
    for (int it = 0; it < 2; ++it) {           // stage x slab [64][64] -> fp16
      int idx = tid + it*256;
      int r = idx >> 3, g8 = idx & 7;
      const float* xp = &x[(size_t)(R0 + r)*OBS + kt*64 + g8*8];
      float4 v0 = *(const float4*)xp;
      float4 v1 = *(const float4*)(xp + 4);
      half8v hv = { (_Float16)v0.x, (_Float16)v0.y, (_Float16)v0.z, (_Float16)v0.w,
                    (_Float16)v1.x, (_Float16)v1.y, (_Float16)v1.z, (_Float16)v1.w };
      *(half8v*)&xs[r*72 + g8*8] = hv;
    }
    stage_wh<128, 256>(W1h, kt*64, wt, tid);
    __syncthreads();
    mfma_slab<8, 72>(xs, wt, rA, ln, quad, acc);
    __syncthreads();
  }
#pragma unroll
  for (int oc = 0; oc < 8; ++oc) {
    int o = oc*16 + ln;
    float bv = b1[o];
#pragma unroll
    for (int r = 0; r < 4; ++r)
      act[(r0 + r)*136 + o] = (_Float16)tanhf(acc[oc][r] + bv);
  }

  // ---- layer 2: 128 -> 128, tanh ----
#pragma unroll
  for (int oc = 0; oc < 8; ++oc) acc[oc] = (f32x4)0.f;
  for (int kt = 0; kt < 2; ++kt) {
    stage_wh<128, 128>(W2h, kt*64, wt, tid);
    __syncthreads();                            // publishes act writes + wt
    mfma_slab<8, 136>(act + kt*64, wt, rA, ln, quad, acc);
    __syncthreads();
  }
#pragma unroll
  for (int oc = 0; oc < 8; ++oc) {
    int o = oc*16 + ln;
    float bv = b2[o];
#pragma unroll
    for (int r = 0; r < 4; ++r)
      act[(r0 + r)*136 + o] = (_Float16)tanhf(acc[oc][r] + bv);
  }

  // ---- layer 3: 128 -> 64, linear -> z into xs buffer ----
#pragma unroll
  for (int oc = 0; oc < 4; ++oc) acc[oc] = (f32x4)0.f;
  for (int kt = 0; kt < 2; ++kt) {
    stage_wh<64, 128>(W3h, kt*64, wt, tid);
    __syncthreads();
    mfma_slab<4, 136>(act + kt*64, wt, rA, ln, quad, acc);
    __syncthreads();
  }
#pragma unroll
  for (int oc = 0; oc < 4; ++oc) {
    int o = oc*16 + ln;
    float bv = b3[o];
#pragma unroll
    for (int r = 0; r < 4; ++r)
      xs[(r0 + r)*72 + o] = (_Float16)(acc[oc][r] + bv);
  }

  // ---- layer 4: z(64) -> 128 gate inputs: z@Wih' + bih + bhh ----
#pragma unroll
  for (int oc = 0; oc < 8; ++oc) acc[oc] = (f32x4)0.f;
  stage_wh<128, 64>(Wihh, 0, wt, tid);
  __syncthreads();                              // publishes z writes + wt
  mfma_slab<8, 72>(xs, wt, rA, ln, quad, acc);
#pragma unroll
  for (int oc = 0; oc < 8; ++oc) {
    int o = oc*16 + ln;
    float badd = bih[o] + bhh[o];
#pragma unroll
    for (int r = 0; r < 4; ++r)
      G1[(size_t)(R0 + r0 + r)*128 + o] = acc[oc][r] + badd;
  }
}

// ---------------------------------------------------------------------------
// LSTM scan v4: 1 row per 64-lane wave, 512 blocks. NO barriers, NO LDS on
// the recurrence: h is broadcast via v_readlane (exec-independent), so the
// G1 prefetch is never drained by a barrier's vmcnt(0) (the v3 failure).
// Lane L computes gates L and L+64; shfl_xor(32) pairs i/g with f/o for the
// c/h update (valid on lanes<32; upper-lane c/h are dead values, never read).
// Depth-3 register prefetch of G1 (~3 iterations > 900 cyc HBM latency).
// ---------------------------------------------------------------------------
__global__ __launch_bounds__(64) void lstm_kernel(
    const float* __restrict__ G1, const float* __restrict__ Whh,
    const int* __restrict__ done, const float* __restrict__ h0,
    const float* __restrict__ c0, float* __restrict__ Y)
{
  __shared__ float md[Tn];
  const int lane = threadIdx.x;        // 0..63
  const int u = lane & 31;
  const int row = blockIdx.x;          // 0..511
  const int b = row >> 5;

  float4 wlo[8], whi[8];               // Whh rows for gates (lane), (lane+64)
#pragma unroll
  for (int k4 = 0; k4 < 8; ++k4) {
    wlo[k4] = *(const float4*)&Whh[lane*HID + k4*4];
    whi[k4] = *(const float4*)&Whh[(64 + lane)*HID + k4*4];
  }
  md[lane]      = 1.f - (float)done[lane*Bn + b];
  md[lane + 64] = 1.f - (float)done[(lane + 64)*Bn + b];
  float h = h0[row*HID + u];
  float c = c0[row*HID + u];
  __syncthreads();                     // once, outside the loop

  // depth-3 prefetch pipeline
  const size_t rb = (size_t)row*128;
  float glA = G1[rb + lane],                      ghA = G1[rb + 64 + lane];
  float glB = G1[(size_t)BA*128 + rb + lane],     ghB = G1[(size_t)BA*128 + rb + 64 + lane];
  float glC = G1[(size_t)2*BA*128 + rb + lane],   ghC = G1[(size_t)2*BA*128 + rb + 64 + lane];
  float mA = md[0], mB = md[1], mC = md[2];

  for (int t = 0; t < Tn; ++t) {
    float gl = glA, gh = ghA, m = mA;
    glA = glB; ghA = ghB; mA = mB;
    glB = glC; ghB = ghC; mB = mC;
    int tp = t + 3; tp = (tp < Tn) ? tp : (Tn - 1);   // clamped, branch-free
    const float* gq = G1 + ((size_t)tp*BA + row)*128;
    glC = gq[lane]; ghC = gq[64 + lane];
    mC = md[tp];

    h *= m; c *= m;

    float pl[4] = { gl, 0.f, 0.f, 0.f };
    float ph[4] = { gh, 0.f, 0.f, 0.f };
#pragma unroll
    for (int k4 = 0; k4 < 8; ++k4) {
      int p = k4 & 3;
      float h0b = bcast_lane(h, k4*4 + 0);
      float h1b = bcast_lane(h, k4*4 + 1);
      float h2b = bcast_lane(h, k4*4 + 2);
      float h3b = bcast_lane(h, k4*4 + 3);
      pl[p] = fmaf(wlo[k4].x, h0b, pl[p]); pl[p] = fmaf(wlo[k4].y, h1b, pl[p]);
      pl[p] = fmaf(wlo[k4].z, h2b, pl[p]); pl[p] = fmaf(wlo[k4].w, h3b, pl[p]);
      ph[p] = fmaf(whi[k4].x, h0b, ph[p]); ph[p] = fmaf(whi[k4].y, h1b, ph[p]);
      ph[p] = fmaf(whi[k4].z, h2b, ph[p]); ph[p] = fmaf(whi[k4].w, h3b, ph[p]);
    }
    gl = (pl[0] + pl[1]) + (pl[2] + pl[3]);
    gh = (ph[0] + ph[1]) + (ph[2] + ph[3]);

    float slo = fast_sig(gl);          // lanes<32: i_u ; lanes>=32: f_u
    float th  = fast_tanh(gh);
    float sh  = fast_sig(gh);
    float ahi = (lane < 32) ? th : sh; // lanes<32: g_u ; lanes>=32: o_u
    float fv = __shfl_xor(slo, 32);    // lanes<32 receive f_u
    float ov = __shfl_xor(ahi, 32);    // lanes<32 receive o_u
    c = fmaf(fv, c, slo * ahi);        // valid on lanes<32
    h = ov * fast_tanh(c);
    if (lane < 32) Y[((size_t)t*BA + row)*HID + u] = h;
  }
}

// ---------------------------------------------------------------------------
// Heads: per row, 27 logits (3 heads x 9), log-softmax, entropy, gather,
// product of chosen log-probs. One thread per row; y staged in LDS (+1 pad).
// ---------------------------------------------------------------------------
__global__ __launch_bounds__(256) void head_kernel(
    const float* __restrict__ Y, const float* __restrict__ Wh,
    const float* __restrict__ bh, const int* __restrict__ actions,
    float* __restrict__ out)
{
  __shared__ float ys[256*33];
  __shared__ __align__(16) float whs[27*32];
  __shared__ float bhs[32];
  const int tid = threadIdx.x;
  const int R0 = blockIdx.x * 256;
  for (int i = tid; i < 27*32; i += 256) whs[i] = Wh[i];
  if (tid < 27) bhs[tid] = bh[tid];
#pragma unroll
  for (int it = 0; it < 8; ++it) {
    int idx = tid + it*256;
    int r = idx >> 3, f4 = idx & 7;
    float4 v = *(const float4*)&Y[(size_t)(R0 + r)*32 + f4*4];
    ys[r*33 + f4*4 + 0] = v.x;
    ys[r*33 + f4*4 + 1] = v.y;
    ys[r*33 + f4*4 + 2] = v.z;
    ys[r*33 + f4*4 + 3] = v.w;
  }
  __syncthreads();
  float yv[32];
#pragma unroll
  for (int k = 0; k < 32; ++k) yv[k] = ys[tid*33 + k];
  float l[27];
#pragma unroll
  for (int m = 0; m < 27; ++m) {
    float a = bhs[m];
#pragma unroll
    for (int k4 = 0; k4 < 8; ++k4) {
      float4 w4 = *(const float4*)&whs[m*32 + k4*4];   // uniform -> broadcast
      a = fmaf(yv[k4*4+0], w4.x, a);
      a = fmaf(yv[k4*4+1], w4.y, a);
      a = fmaf(yv[k4*4+2], w4.z, a);
      a = fmaf(yv[k4*4+3], w4.w, a);
    }
    l[m] = a;
  }
  const int row = R0 + tid;
  float logprob = 1.0f;
#pragma unroll
  for (int kk = 0; kk < 3; ++kk) {
    float mx = l[kk*9];
#pragma unroll
    for (int n = 1; n < 9; ++n) mx = fmaxf(mx, l[kk*9+n]);
    float s = 0.f;
#pragma unroll
    for (int n = 0; n < 9; ++n) s += __expf(l[kk*9+n] - mx);
    float lse = mx + __logf(s);
    float ent = 0.f;
#pragma unroll
    for (int n = 0; n < 9; ++n) {
      float lp = l[kk*9+n] - lse;
      ent -= __expf(lp) * lp;
    }
    int a = actions[row*3 + kk];
    float alp = 0.f;
#pragma unroll
    for (int n = 0; n < 9; ++n) alp = (a == n) ? (l[kk*9+n] - lse) : alp;
    logprob *= alp;
    out[row*3 + kk] = (float)a;          // actions echoed as float
    out[OUT_ENT + row*3 + kk] = ent;
  }
  out[OUT_LP + row] = logprob;
}

extern "C" void kernel_launch(void* const* d_in, const int* in_sizes, int n_in,
                              void* d_out, int out_size, void* d_ws, size_t ws_size,
                              hipStream_t stream)
{
  const float* x       = (const float*)d_in[0];
  const int*   done    = (const int*)  d_in[1];
  const int*   actions = (const int*)  d_in[2];
  const float* W1  = (const float*)d_in[3];
  const float* b1  = (const float*)d_in[4];
  const float* W2  = (const float*)d_in[5];
  const float* b2  = (const float*)d_in[6];
  const float* W3  = (const float*)d_in[7];
  const float* b3  = (const float*)d_in[8];
  const float* Wih = (const float*)d_in[9];
  const float* Whh = (const float*)d_in[10];
  const float* bih = (const float*)d_in[11];
  const float* bhh = (const float*)d_in[12];
  const float* Wh  = (const float*)d_in[13];
  const float* bh  = (const float*)d_in[14];
  const float* h0  = (const float*)d_in[15];
  const float* c0  = (const float*)d_in[16];
  float* out = (float*)d_out;

  float* G1 = (float*)d_ws;                      // [65536][128] f32 = 33.5 MB
  float* Y  = G1 + (size_t)TBA * 128;            // [65536][32]  f32 =  8.4 MB
  _Float16* W16 = (_Float16*)(Y + (size_t)TBA * 32);  // 65536 halfs = 128 KB

  cvtw_kernel<<<W16_TOT/256, 256, 0, stream>>>(W1, W2, W3, Wih, W16);
  mlp_kernel<<<TBA/64, 256, 0, stream>>>(x, W16, b1, b2, b3, bih, bhh, G1);
  lstm_kernel<<<BA, 64, 0, stream>>>(G1, Whh, done, h0, c0, Y);
  head_kernel<<<TBA/256, 256, 0, stream>>>(Y, Wh, bh, actions, out);
}

// Round 7
// 204.185 us; speedup vs baseline: 1.1782x; 1.0779x over previous
//
#include <hip/hip_runtime.h>
#include <math.h>

namespace {
constexpr int Tn = 128, Bn = 16, An = 32, OBS = 256, Kh = 3, NACT = 9, HID = 32;
constexpr int TBA = Tn * Bn * An;   // 65536 rows through the MLP
constexpr int BA  = Bn * An;        // 512 LSTM sequences
constexpr int OUT_LP  = TBA * Kh;         // 196608: logprobs start
constexpr int OUT_ENT = TBA * Kh + TBA;   // 262144: entropies start

// fp16 weight pack offsets (elements)
constexpr int W1_OFF  = 0;       // 128x256
constexpr int W2_OFF  = 32768;   // 128x128
constexpr int W3_OFF  = 49152;   // 64x128
constexpr int WIH_OFF = 57344;   // 128x64
constexpr int W16_TOT = 65536;

typedef __fp16   pk16x2 __attribute__((ext_vector_type(2)));  // builtin-compatible
typedef _Float16 half4v __attribute__((ext_vector_type(4)));
typedef _Float16 half8v __attribute__((ext_vector_type(8)));
typedef float    f32x4  __attribute__((ext_vector_type(4)));
}

__device__ __forceinline__ float fast_sig(float x) {
  return __builtin_amdgcn_rcpf(1.f + __expf(-x));
}
__device__ __forceinline__ float fast_tanh(float x) {   // 2*sig(2x)-1, saturates safely
  return fmaf(2.f, fast_sig(2.f * x), -1.f);
}
__device__ __forceinline__ unsigned h2bits(pk16x2 h) {
  return __builtin_bit_cast(unsigned, h);
}
__device__ __forceinline__ pk16x2 bits2h(unsigned u) {
  return __builtin_bit_cast(pk16x2, u);
}

__device__ __forceinline__ float dot2(pk16x2 a, pk16x2 b, float c) {
#if __has_builtin(__builtin_amdgcn_fdot2)
  return __builtin_amdgcn_fdot2(a, b, c, false);
#else
  c = fmaf((float)a.x, (float)b.x, c);
  return fmaf((float)a.y, (float)b.y, c);
#endif
}

// ---------------------------------------------------------------------------
// Weight pre-conversion: all four matrices fp32 -> fp16 once per call.
// ---------------------------------------------------------------------------
__global__ __launch_bounds__(256) void cvtw_kernel(
    const float* __restrict__ W1, const float* __restrict__ W2,
    const float* __restrict__ W3, const float* __restrict__ Wih,
    _Float16* __restrict__ w16)
{
  int i = blockIdx.x * 256 + threadIdx.x;       // 0..65535
  float v;
  if (i < W2_OFF)       v = W1[i];
  else if (i < W3_OFF)  v = W2[i - W2_OFF];
  else if (i < WIH_OFF) v = W3[i - W3_OFF];
  else                  v = Wih[i - WIH_OFF];
  w16[i] = (_Float16)v;
}

// ---------------------------------------------------------------------------
// Fused MLP trunk + LSTM input projection, f16 MFMA (fp32 accumulate):
//   z = tanh(tanh(x@W1'+b1)@W2'+b2)@W3'+b3 ; G1 = z@Wih' + bih + bhh
// G1 stored as packed fp16 pairs (gate j, gate j+64) -> 16.8 MB.
// ---------------------------------------------------------------------------
template<int ROWS, int WSTR>
__device__ __forceinline__ void stage_wh(const _Float16* __restrict__ Wg, int kofs,
                                         _Float16* __restrict__ wt, int tid)
{
#pragma unroll
  for (int it = 0; it < ROWS/32; ++it) {
    int idx = tid + it*256;
    int o = idx >> 3, g8 = idx & 7;
    *(half8v*)&wt[o*72 + g8*8] =
        *(const half8v*)&Wg[(size_t)o*WSTR + kofs + g8*8];
  }
}

template<int NOC, int XSTR>
__device__ __forceinline__ void mfma_slab(const _Float16* __restrict__ xsrc,
                                          const _Float16* __restrict__ wt,
                                          int rA, int ln, int quad, f32x4 acc[8])
{
#pragma unroll
  for (int kc = 0; kc < 2; ++kc) {
    half8v a = *(const half8v*)&xsrc[rA*XSTR + kc*32 + quad*8];
#pragma unroll
    for (int oc = 0; oc < NOC; ++oc) {
      half8v b = *(const half8v*)&wt[(oc*16 + ln)*72 + kc*32 + quad*8];
      acc[oc] = __builtin_amdgcn_mfma_f32_16x16x32_f16(a, b, acc[oc], 0, 0, 0);
    }
  }
}

__global__ __launch_bounds__(256) void mlp_kernel(
    const float* __restrict__ x, const _Float16* __restrict__ w16,
    const float* __restrict__ b1, const float* __restrict__ b2,
    const float* __restrict__ b3, const float* __restrict__ bih,
    const float* __restrict__ bhh, unsigned* __restrict__ G1p)
{
  __shared__ __align__(16) _Float16 xs[64*72];    // x k-slab; reused for z
  __shared__ __align__(16) _Float16 wt[128*72];   // weight k-slab
  __shared__ __align__(16) _Float16 act[64*136];  // activations (reused in place)
  const _Float16* W1h  = w16 + W1_OFF;
  const _Float16* W2h  = w16 + W2_OFF;
  const _Float16* W3h  = w16 + W3_OFF;
  const _Float16* Wihh = w16 + WIH_OFF;
  const int tid  = threadIdx.x;
  const int w    = tid >> 6;
  const int lane = tid & 63;
  const int ln   = lane & 15;
  const int quad = lane >> 4;
  const int rA   = 16*w + ln;
  const int r0   = 16*w + quad*4;
  const int R0   = blockIdx.x * 64;
  f32x4 acc[8];

  // ---- layer 1: 256 -> 128, tanh (4 k-slabs of 64) ----
#pragma unroll
  for (int oc = 0; oc < 8; ++oc) acc[oc] = (f32x4)0.f;
  for (int kt = 0; kt < 4; ++kt) {
#pragma unroll
    for (int it = 0; it < 2; ++it) {           // stage x slab [64][64] -> fp16
      int idx = tid + it*256;
      int r = idx >> 3, g8 = idx & 7;
      const float* xp = &x[(size_t)(R0 + r)*OBS + kt*64 + g8*8];
      float4 v0 = *(const float4*)xp;
      float4 v1 = *(const float4*)(xp + 4);
      half8v hv = { (_Float16)v0.x, (_Float16)v0.y, (_Float16)v0.z, (_Float16)v0.w,
                    (_Float16)v1.x, (_Float16)v1.y, (_Float16)v1.z, (_Float16)v1.w };
      *(half8v*)&xs[r*72 + g8*8] = hv;
    }
    stage_wh<128, 256>(W1h, kt*64, wt, tid);
    __syncthreads();
    mfma_slab<8, 72>(xs, wt, rA, ln, quad, acc);
    __syncthreads();
  }
#pragma unroll
  for (int oc = 0; oc < 8; ++oc) {
    int o = oc*16 + ln;
    float bv = b1[o];
#pragma unroll
    for (int r = 0; r < 4; ++r)
      act[(r0 + r)*136 + o] = (_Float16)fast_tanh(acc[oc][r] + bv);
  }

  // ---- layer 2: 128 -> 128, tanh ----
#pragma unroll
  for (int oc = 0; oc < 8; ++oc) acc[oc] = (f32x4)0.f;
  for (int kt = 0; kt < 2; ++kt) {
    stage_wh<128, 128>(W2h, kt*64, wt, tid);
    __syncthreads();                            // publishes act writes + wt
    mfma_slab<8, 136>(act + kt*64, wt, rA, ln, quad, acc);
    __syncthreads();
  }
#pragma unroll
  for (int oc = 0; oc < 8; ++oc) {
    int o = oc*16 + ln;
    float bv = b2[o];
#pragma unroll
    for (int r = 0; r < 4; ++r)
      act[(r0 + r)*136 + o] = (_Float16)fast_tanh(acc[oc][r] + bv);
  }

  // ---- layer 3: 128 -> 64, linear -> z into xs buffer ----
#pragma unroll
  for (int oc = 0; oc < 4; ++oc) acc[oc] = (f32x4)0.f;
  for (int kt = 0; kt < 2; ++kt) {
    stage_wh<64, 128>(W3h, kt*64, wt, tid);
    __syncthreads();
    mfma_slab<4, 136>(act + kt*64, wt, rA, ln, quad, acc);
    __syncthreads();
  }
#pragma unroll
  for (int oc = 0; oc < 4; ++oc) {
    int o = oc*16 + ln;
    float bv = b3[o];
#pragma unroll
    for (int r = 0; r < 4; ++r)
      xs[(r0 + r)*72 + o] = (_Float16)(acc[oc][r] + bv);
  }

  // ---- layer 4: z(64) -> 128 gate inputs, packed (j, j+64) fp16 pairs ----
#pragma unroll
  for (int oc = 0; oc < 8; ++oc) acc[oc] = (f32x4)0.f;
  stage_wh<128, 64>(Wihh, 0, wt, tid);
  __syncthreads();                              // publishes z writes + wt
  mfma_slab<8, 72>(xs, wt, rA, ln, quad, acc);
#pragma unroll
  for (int oc = 0; oc < 4; ++oc) {
    int o  = oc*16 + ln;            // gate j
    int oh = o + 64;                // gate j+64
    float blo = bih[o]  + bhh[o];
    float bhi = bih[oh] + bhh[oh];
#pragma unroll
    for (int r = 0; r < 4; ++r) {
      pk16x2 p = __builtin_amdgcn_cvt_pkrtz(acc[oc][r] + blo, acc[oc+4][r] + bhi);
      G1p[(size_t)(R0 + r0 + r)*64 + o] = h2bits(p);
    }
  }
}

// ---------------------------------------------------------------------------
// LSTM scan v5: 1 row per 64-lane wave, 512 blocks, barrier-free recurrence.
// State: c (fp32) + pk (packed fp16 pair of h for units (u,u+1), even lanes).
// Per step: 16 readlanes broadcast the 16 h-pairs; 32 v_dot2_f32_f16 compute
// the two 32-dots (gates L and L+64). done-mask m is wave-uniform -> folded
// as gl = G1 + m*dot. gh activation: tanh(lanes<32)/sig(lanes>=32) via one
// sigmoid with per-lane affine constants. f,o exchanged with ONE packed
// shfl_xor(32). G1p (packed pairs) prefetched depth-3.
// ---------------------------------------------------------------------------
__global__ __launch_bounds__(64) void lstm_kernel(
    const unsigned* __restrict__ G1p, const float* __restrict__ Whh,
    const int* __restrict__ done, const float* __restrict__ h0,
    const float* __restrict__ c0, unsigned* __restrict__ Y16)
{
  __shared__ float md[Tn];
  const int lane = threadIdx.x;        // 0..63
  const int u = lane & 31;
  const int row = blockIdx.x;          // 0..511
  const int b = row >> 5;

  pk16x2 wlo[16], whi[16];             // Whh rows for gates (lane), (lane+64)
#pragma unroll
  for (int k4 = 0; k4 < 8; ++k4) {
    float4 a = *(const float4*)&Whh[lane*HID + k4*4];
    float4 bq = *(const float4*)&Whh[(64 + lane)*HID + k4*4];
    wlo[2*k4+0] = __builtin_amdgcn_cvt_pkrtz(a.x, a.y);
    wlo[2*k4+1] = __builtin_amdgcn_cvt_pkrtz(a.z, a.w);
    whi[2*k4+0] = __builtin_amdgcn_cvt_pkrtz(bq.x, bq.y);
    whi[2*k4+1] = __builtin_amdgcn_cvt_pkrtz(bq.z, bq.w);
  }
  md[lane]      = 1.f - (float)done[lane*Bn + b];
  md[lane + 64] = 1.f - (float)done[(lane + 64)*Bn + b];
  float c = c0[row*HID + u];
  float h = h0[row*HID + u];
  __syncthreads();                     // once, outside the loop

  // initial packed h pair (valid on even lanes)
  float hsw = __shfl_xor(h, 1);
  unsigned pk = h2bits(__builtin_amdgcn_cvt_pkrtz(h, hsw));

  // per-lane activation constants for the gh path
  const float sA = (lane < 32) ? 2.f : 1.f;
  const float cA = (lane < 32) ? 2.f : 1.f;
  const float cB = (lane < 32) ? -1.f : 0.f;

  // depth-3 prefetch of packed gate inputs (1 dword per step)
  const size_t rb = (size_t)row*64;
  unsigned gA = G1p[rb + lane];
  unsigned gB = G1p[(size_t)BA*64 + rb + lane];
  unsigned gC = G1p[(size_t)2*BA*64 + rb + lane];
  float mA = md[0], mB = md[1], mC = md[2];

  for (int t = 0; t < Tn; ++t) {
    unsigned gp = gA; gA = gB; gB = gC;
    float m = mA; mA = mB; mB = mC;
    int tp = t + 3; tp = (tp < Tn) ? tp : (Tn - 1);   // clamped, branch-free
    gC = G1p[(size_t)tp*BA*64 + rb + lane];
    mC = md[tp];

    // broadcast the 16 h-pairs (from even lanes 0,2,..,30)
    unsigned hp[16];
#pragma unroll
    for (int k = 0; k < 16; ++k)
      hp[k] = __builtin_amdgcn_readlane(pk, 2*k);

    pk16x2 gph = bits2h(gp);
    float pl[4] = { 0.f, 0.f, 0.f, 0.f };
    float ph[4] = { 0.f, 0.f, 0.f, 0.f };
#pragma unroll
    for (int k = 0; k < 16; ++k) {
      int p = k & 3;
      pk16x2 hk = bits2h(hp[k]);
      pl[p] = dot2(wlo[k], hk, pl[p]);
      ph[p] = dot2(whi[k], hk, ph[p]);
    }
    float gl = fmaf(m, (pl[0] + pl[1]) + (pl[2] + pl[3]), (float)gph.x);
    float gh = fmaf(m, (ph[0] + ph[1]) + (ph[2] + ph[3]), (float)gph.y);

    float slo = fast_sig(gl);                      // i (lanes<32) or f
    float ahi = fmaf(cA, fast_sig(sA * gh), cB);   // g=tanh (lanes<32) or o=sig
    unsigned pr = h2bits(__builtin_amdgcn_cvt_pkrtz(slo, ahi));
    unsigned qr = __shfl_xor(pr, 32);
    pk16x2 qh = bits2h(qr);
    float fv = (float)qh.x;            // f_u (valid on lanes<32)
    float ov = (float)qh.y;            // o_u

    c = fmaf(fv, m * c, slo * ahi);    // c masked; valid on lanes<32
    h = ov * fast_tanh(c);

    hsw = __shfl_xor(h, 1);            // DPP quad-perm: cheap
    pk = h2bits(__builtin_amdgcn_cvt_pkrtz(h, hsw));
    if ((lane & 33) == 0)              // even lanes < 32 store the pair
      Y16[((size_t)t*BA + row)*16 + (u >> 1)] = pk;
  }
}

// ---------------------------------------------------------------------------
// Heads: per row, 27 logits (3 heads x 9), log-softmax, entropy, gather,
// product of chosen log-probs. One thread per row; Y (fp16 pairs) read
// directly from global (single use - no LDS staging).
// ---------------------------------------------------------------------------
__global__ __launch_bounds__(256) void head_kernel(
    const unsigned* __restrict__ Y16, const float* __restrict__ Wh,
    const float* __restrict__ bh, const int* __restrict__ actions,
    float* __restrict__ out)
{
  __shared__ __align__(16) float whs[27*32];
  __shared__ float bhs[32];
  const int tid = threadIdx.x;
  const int R0 = blockIdx.x * 256;
  for (int i = tid; i < 27*32; i += 256) whs[i] = Wh[i];
  if (tid < 27) bhs[tid] = bh[tid];
  const int row = R0 + tid;
  float yv[32];
#pragma unroll
  for (int i4 = 0; i4 < 4; ++i4) {
    uint4 yw = *(const uint4*)&Y16[(size_t)row*16 + i4*4];
    pk16x2 p0 = bits2h(yw.x), p1 = bits2h(yw.y), p2 = bits2h(yw.z), p3 = bits2h(yw.w);
    yv[i4*8+0] = (float)p0.x; yv[i4*8+1] = (float)p0.y;
    yv[i4*8+2] = (float)p1.x; yv[i4*8+3] = (float)p1.y;
    yv[i4*8+4] = (float)p2.x; yv[i4*8+5] = (float)p2.y;
    yv[i4*8+6] = (float)p3.x; yv[i4*8+7] = (float)p3.y;
  }
  __syncthreads();
  float l[27];
#pragma unroll
  for (int m = 0; m < 27; ++m) {
    float a = bhs[m];
#pragma unroll
    for (int k4 = 0; k4 < 8; ++k4) {
      float4 w4 = *(const float4*)&whs[m*32 + k4*4];   // uniform -> broadcast
      a = fmaf(yv[k4*4+0], w4.x, a);
      a = fmaf(yv[k4*4+1], w4.y, a);
      a = fmaf(yv[k4*4+2], w4.z, a);
      a = fmaf(yv[k4*4+3], w4.w, a);
    }
    l[m] = a;
  }
  float logprob = 1.0f;
#pragma unroll
  for (int kk = 0; kk < 3; ++kk) {
    float mx = l[kk*9];
#pragma unroll
    for (int n = 1; n < 9; ++n) mx = fmaxf(mx, l[kk*9+n]);
    float s = 0.f;
#pragma unroll
    for (int n = 0; n < 9; ++n) s += __expf(l[kk*9+n] - mx);
    float lse = mx + __logf(s);
    float ent = 0.f;
#pragma unroll
    for (int n = 0; n < 9; ++n) {
      float lp = l[kk*9+n] - lse;
      ent -= __expf(lp) * lp;
    }
    int a = actions[row*3 + kk];
    float alp = 0.f;
#pragma unroll
    for (int n = 0; n < 9; ++n) alp = (a == n) ? (l[kk*9+n] - lse) : alp;
    logprob *= alp;
    out[row*3 + kk] = (float)a;          // actions echoed as float
    out[OUT_ENT + row*3 + kk] = ent;
  }
  out[OUT_LP + row] = logprob;
}

extern "C" void kernel_launch(void* const* d_in, const int* in_sizes, int n_in,
                              void* d_out, int out_size, void* d_ws, size_t ws_size,
                              hipStream_t stream)
{
  const float* x       = (const float*)d_in[0];
  const int*   done    = (const int*)  d_in[1];
  const int*   actions = (const int*)  d_in[2];
  const float* W1  = (const float*)d_in[3];
  const float* b1  = (const float*)d_in[4];
  const float* W2  = (const float*)d_in[5];
  const float* b2  = (const float*)d_in[6];
  const float* W3  = (const float*)d_in[7];
  const float* b3  = (const float*)d_in[8];
  const float* Wih = (const float*)d_in[9];
  const float* Whh = (const float*)d_in[10];
  const float* bih = (const float*)d_in[11];
  const float* bhh = (const float*)d_in[12];
  const float* Wh  = (const float*)d_in[13];
  const float* bh  = (const float*)d_in[14];
  const float* h0  = (const float*)d_in[15];
  const float* c0  = (const float*)d_in[16];
  float* out = (float*)d_out;

  unsigned* G1p = (unsigned*)d_ws;                   // TBA*64 uints = 16.8 MB
  unsigned* Y16 = G1p + (size_t)TBA*64;              // TBA*16 uints =  4.2 MB
  _Float16* W16 = (_Float16*)(Y16 + (size_t)TBA*16); // 128 KB

  cvtw_kernel<<<W16_TOT/256, 256, 0, stream>>>(W1, W2, W3, Wih, W16);
  mlp_kernel<<<TBA/64, 256, 0, stream>>>(x, W16, b1, b2, b3, bih, bhh, G1p);
  lstm_kernel<<<BA, 64, 0, stream>>>(G1p, Whh, done, h0, c0, Y16);
  head_kernel<<<TBA/256, 256, 0, stream>>>(Y16, Wh, bh, actions, out);
}

// Round 8
// 200.691 us; speedup vs baseline: 1.1987x; 1.0174x over previous
//
#include <hip/hip_runtime.h>
#include <math.h>

namespace {
constexpr int Tn = 128, Bn = 16, An = 32, OBS = 256, Kh = 3, NACT = 9, HID = 32;
constexpr int TBA = Tn * Bn * An;   // 65536 rows through the MLP
constexpr int BA  = Bn * An;        // 512 LSTM sequences
constexpr int OUT_LP  = TBA * Kh;         // 196608: logprobs start
constexpr int OUT_ENT = TBA * Kh + TBA;   // 262144: entropies start

// fp16 weight pack offsets (elements)
constexpr int W1_OFF  = 0;       // 128x256
constexpr int W2_OFF  = 32768;   // 128x128
constexpr int W3_OFF  = 49152;   // 64x128
constexpr int WIH_OFF = 57344;   // 128x64
constexpr int W16_TOT = 65536;

typedef __fp16   pk16x2 __attribute__((ext_vector_type(2)));  // builtin-compatible
typedef _Float16 half8v __attribute__((ext_vector_type(8)));
typedef float    f32x4  __attribute__((ext_vector_type(4)));
}

__device__ __forceinline__ float fast_sig(float x) {
  return __builtin_amdgcn_rcpf(1.f + __expf(-x));
}
__device__ __forceinline__ float fast_tanh(float x) {   // 2*sig(2x)-1, saturates safely
  return fmaf(2.f, fast_sig(2.f * x), -1.f);
}
__device__ __forceinline__ unsigned h2bits(pk16x2 h) {
  return __builtin_bit_cast(unsigned, h);
}
__device__ __forceinline__ pk16x2 bits2h(unsigned u) {
  return __builtin_bit_cast(pk16x2, u);
}
__device__ __forceinline__ float dot2(pk16x2 a, pk16x2 b, float c) {
#if __has_builtin(__builtin_amdgcn_fdot2)
  return __builtin_amdgcn_fdot2(a, b, c, false);
#else
  c = fmaf((float)a.x, (float)b.x, c);
  return fmaf((float)a.y, (float)b.y, c);
#endif
}

// ---------------------------------------------------------------------------
// Weight pre-conversion: all four matrices fp32 -> fp16 once per call.
// ---------------------------------------------------------------------------
__global__ __launch_bounds__(256) void cvtw_kernel(
    const float* __restrict__ W1, const float* __restrict__ W2,
    const float* __restrict__ W3, const float* __restrict__ Wih,
    _Float16* __restrict__ w16)
{
  int i = blockIdx.x * 256 + threadIdx.x;       // 0..65535
  float v;
  if (i < W2_OFF)       v = W1[i];
  else if (i < W3_OFF)  v = W2[i - W2_OFF];
  else if (i < WIH_OFF) v = W3[i - W3_OFF];
  else                  v = Wih[i - WIH_OFF];
  w16[i] = (_Float16)v;
}

// ---------------------------------------------------------------------------
// Fused MLP trunk + LSTM input projection, f16 MFMA (fp32 accumulate):
//   z = tanh(tanh(x@W1'+b1)@W2'+b2)@W3'+b3 ; G1 = z@Wih' + bih + bhh
// G1 stored as uint2 per (row, unit): {pk(i,g), pk(f,o)} -> one dwordx2
// load per LSTM step per lane.
// ---------------------------------------------------------------------------
template<int ROWS, int WSTR>
__device__ __forceinline__ void stage_wh(const _Float16* __restrict__ Wg, int kofs,
                                         _Float16* __restrict__ wt, int tid)
{
#pragma unroll
  for (int it = 0; it < ROWS/32; ++it) {
    int idx = tid + it*256;
    int o = idx >> 3, g8 = idx & 7;
    *(half8v*)&wt[o*72 + g8*8] =
        *(const half8v*)&Wg[(size_t)o*WSTR + kofs + g8*8];
  }
}

template<int NOC, int XSTR>
__device__ __forceinline__ void mfma_slab(const _Float16* __restrict__ xsrc,
                                          const _Float16* __restrict__ wt,
                                          int rA, int ln, int quad, f32x4 acc[8])
{
#pragma unroll
  for (int kc = 0; kc < 2; ++kc) {
    half8v a = *(const half8v*)&xsrc[rA*XSTR + kc*32 + quad*8];
#pragma unroll
    for (int oc = 0; oc < NOC; ++oc) {
      half8v b = *(const half8v*)&wt[(oc*16 + ln)*72 + kc*32 + quad*8];
      acc[oc] = __builtin_amdgcn_mfma_f32_16x16x32_f16(a, b, acc[oc], 0, 0, 0);
    }
  }
}

__global__ __launch_bounds__(256) void mlp_kernel(
    const float* __restrict__ x, const _Float16* __restrict__ w16,
    const float* __restrict__ b1, const float* __restrict__ b2,
    const float* __restrict__ b3, const float* __restrict__ bih,
    const float* __restrict__ bhh, uint2* __restrict__ G1q)
{
  __shared__ __align__(16) _Float16 xs[64*72];    // x k-slab; reused for z
  __shared__ __align__(16) _Float16 wt[128*72];   // weight k-slab
  __shared__ __align__(16) _Float16 act[64*136];  // activations (reused in place)
  const _Float16* W1h  = w16 + W1_OFF;
  const _Float16* W2h  = w16 + W2_OFF;
  const _Float16* W3h  = w16 + W3_OFF;
  const _Float16* Wihh = w16 + WIH_OFF;
  const int tid  = threadIdx.x;
  const int w    = tid >> 6;
  const int lane = tid & 63;
  const int ln   = lane & 15;
  const int quad = lane >> 4;
  const int rA   = 16*w + ln;
  const int r0   = 16*w + quad*4;
  const int R0   = blockIdx.x * 64;
  f32x4 acc[8];

  // ---- layer 1: 256 -> 128, tanh (4 k-slabs of 64) ----
#pragma unroll
  for (int oc = 0; oc < 8; ++oc) acc[oc] = (f32x4)0.f;
  for (int kt = 0; kt < 4; ++kt) {
#pragma unroll
    for (int it = 0; it < 2; ++it) {           // stage x slab [64][64] -> fp16
      int idx = tid + it*256;
      int r = idx >> 3, g8 = idx & 7;
      const float* xp = &x[(size_t)(R0 + r)*OBS + kt*64 + g8*8];
      float4 v0 = *(const float4*)xp;
      float4 v1 = *(const float4*)(xp + 4);
      half8v hv = { (_Float16)v0.x, (_Float16)v0.y, (_Float16)v0.z, (_Float16)v0.w,
                    (_Float16)v1.x, (_Float16)v1.y, (_Float16)v1.z, (_Float16)v1.w };
      *(half8v*)&xs[r*72 + g8*8] = hv;
    }
    stage_wh<128, 256>(W1h, kt*64, wt, tid);
    __syncthreads();
    mfma_slab<8, 72>(xs, wt, rA, ln, quad, acc);
    __syncthreads();
  }
#pragma unroll
  for (int oc = 0; oc < 8; ++oc) {
    int o = oc*16 + ln;
    float bv = b1[o];
#pragma unroll
    for (int r = 0; r < 4; ++r)
      act[(r0 + r)*136 + o] = (_Float16)fast_tanh(acc[oc][r] + bv);
  }

  // ---- layer 2: 128 -> 128, tanh ----
#pragma unroll
  for (int oc = 0; oc < 8; ++oc) acc[oc] = (f32x4)0.f;
  for (int kt = 0; kt < 2; ++kt) {
    stage_wh<128, 128>(W2h, kt*64, wt, tid);
    __syncthreads();                            // publishes act writes + wt
    mfma_slab<8, 136>(act + kt*64, wt, rA, ln, quad, acc);
    __syncthreads();
  }
#pragma unroll
  for (int oc = 0; oc < 8; ++oc) {
    int o = oc*16 + ln;
    float bv = b2[o];
#pragma unroll
    for (int r = 0; r < 4; ++r)
      act[(r0 + r)*136 + o] = (_Float16)fast_tanh(acc[oc][r] + bv);
  }

  // ---- layer 3: 128 -> 64, linear -> z into xs buffer ----
#pragma unroll
  for (int oc = 0; oc < 4; ++oc) acc[oc] = (f32x4)0.f;
  for (int kt = 0; kt < 2; ++kt) {
    stage_wh<64, 128>(W3h, kt*64, wt, tid);
    __syncthreads();
    mfma_slab<4, 136>(act + kt*64, wt, rA, ln, quad, acc);
    __syncthreads();
  }
#pragma unroll
  for (int oc = 0; oc < 4; ++oc) {
    int o = oc*16 + ln;
    float bv = b3[o];
#pragma unroll
    for (int r = 0; r < 4; ++r)
      xs[(r0 + r)*72 + o] = (_Float16)(acc[oc][r] + bv);
  }

  // ---- layer 4: z(64) -> 128 gate inputs, all 4 gates of unit u packed ----
  // gate index = oc*16 + ln; unit ui = p*16+ln has i=acc[p], f=acc[p+2],
  // g=acc[p+4], o=acc[p+6]  -> uint2 { pk(i,g), pk(f,o) } at G1q[n*32+ui].
#pragma unroll
  for (int oc = 0; oc < 8; ++oc) acc[oc] = (f32x4)0.f;
  stage_wh<128, 64>(Wihh, 0, wt, tid);
  __syncthreads();                              // publishes z writes + wt
  mfma_slab<8, 72>(xs, wt, rA, ln, quad, acc);
#pragma unroll
  for (int p = 0; p < 2; ++p) {
    int ui = p*16 + ln;
    float bi = bih[ui]      + bhh[ui];
    float bf = bih[ui + 32] + bhh[ui + 32];
    float bg = bih[ui + 64] + bhh[ui + 64];
    float bo = bih[ui + 96] + bhh[ui + 96];
#pragma unroll
    for (int r = 0; r < 4; ++r) {
      int n = R0 + r0 + r;
      uint2 q;
      q.x = h2bits(__builtin_amdgcn_cvt_pkrtz(acc[p  ][r] + bi, acc[p+4][r] + bg));
      q.y = h2bits(__builtin_amdgcn_cvt_pkrtz(acc[p+2][r] + bf, acc[p+6][r] + bo));
      G1q[(size_t)n*32 + ui] = q;
    }
  }
}

// ---------------------------------------------------------------------------
// LSTM scan v6: 1 row per 64-lane wave, 512 blocks, barrier-free.
// Every lane computes ALL 4 gates of unit u=lane&31 (upper half duplicates -
// free under wave64): no cross-32 shuffle on the chain; only a cheap DPP
// shfl_xor(1) for h-pair packing + 16 readlane broadcasts.
// G1 loads are a manual 4-phase software pipeline with DISTINCT registers
// (no rotation), so the compiler can wait vmcnt(3): ~3 iterations of slack
// covers the ~900-cycle HBM miss latency (v5's rotating prefetch only ever
// had 1 iteration of slack -> ~500 cyc stall per step).
// ---------------------------------------------------------------------------
__global__ __launch_bounds__(64) void lstm_kernel(
    const uint2* __restrict__ G1q, const float* __restrict__ Whh,
    const int* __restrict__ done, const float* __restrict__ h0,
    const float* __restrict__ c0, unsigned* __restrict__ Y16)
{
  __shared__ float md[Tn];
  const int lane = threadIdx.x;        // 0..63
  const int u = lane & 31;
  const int row = blockIdx.x;          // 0..511
  const int b = row >> 5;

  pk16x2 wi[16], wf[16], wg[16], wo[16];   // Whh rows u, u+32, u+64, u+96
#pragma unroll
  for (int k4 = 0; k4 < 8; ++k4) {
    float4 a  = *(const float4*)&Whh[(u      )*HID + k4*4];
    float4 bq = *(const float4*)&Whh[(u + 32 )*HID + k4*4];
    float4 cq = *(const float4*)&Whh[(u + 64 )*HID + k4*4];
    float4 dq = *(const float4*)&Whh[(u + 96 )*HID + k4*4];
    wi[2*k4+0] = __builtin_amdgcn_cvt_pkrtz(a.x,  a.y);
    wi[2*k4+1] = __builtin_amdgcn_cvt_pkrtz(a.z,  a.w);
    wf[2*k4+0] = __builtin_amdgcn_cvt_pkrtz(bq.x, bq.y);
    wf[2*k4+1] = __builtin_amdgcn_cvt_pkrtz(bq.z, bq.w);
    wg[2*k4+0] = __builtin_amdgcn_cvt_pkrtz(cq.x, cq.y);
    wg[2*k4+1] = __builtin_amdgcn_cvt_pkrtz(cq.z, cq.w);
    wo[2*k4+0] = __builtin_amdgcn_cvt_pkrtz(dq.x, dq.y);
    wo[2*k4+1] = __builtin_amdgcn_cvt_pkrtz(dq.z, dq.w);
  }
  md[lane]      = 1.f - (float)done[lane*Bn + b];
  md[lane + 64] = 1.f - (float)done[(lane + 64)*Bn + b];
  float c = c0[row*HID + u];
  float h = h0[row*HID + u];
  __syncthreads();                     // once, outside the loop

  float hsw = __shfl_xor(h, 1);
  unsigned pk = h2bits(__builtin_amdgcn_cvt_pkrtz(h, hsw));

  const uint2* gbase = G1q + (size_t)row*32 + u;
  const size_t gstride = (size_t)BA*32;          // uint2 per step
  uint2 q0 = gbase[0*gstride];
  uint2 q1 = gbase[1*gstride];
  uint2 q2 = gbase[2*gstride];
  uint2 q3 = gbase[3*gstride];

#define LSTM_PHASE(TT, Q)                                                \
  {                                                                      \
    uint2 cur = Q;                                                       \
    int tnx = (TT) + 4; tnx = (tnx < Tn) ? tnx : (Tn - 1);               \
    Q = gbase[(size_t)tnx * gstride];                                    \
    float m = md[(TT)];                                                  \
    unsigned hp[16];                                                     \
    _Pragma("unroll") for (int k = 0; k < 16; ++k)                       \
      hp[k] = __builtin_amdgcn_readlane(pk, 2*k);                        \
    float ai0=0.f, ai1=0.f, af0=0.f, af1=0.f;                            \
    float ag0=0.f, ag1=0.f, ao0=0.f, ao1=0.f;                            \
    _Pragma("unroll") for (int k = 0; k < 16; k += 2) {                  \
      pk16x2 ha = bits2h(hp[k]), hb = bits2h(hp[k+1]);                   \
      ai0 = dot2(wi[k], ha, ai0); ai1 = dot2(wi[k+1], hb, ai1);          \
      af0 = dot2(wf[k], ha, af0); af1 = dot2(wf[k+1], hb, af1);          \
      ag0 = dot2(wg[k], ha, ag0); ag1 = dot2(wg[k+1], hb, ag1);          \
      ao0 = dot2(wo[k], ha, ao0); ao1 = dot2(wo[k+1], hb, ao1);          \
    }                                                                    \
    pk16x2 ig = bits2h(cur.x), fo = bits2h(cur.y);                       \
    float gi = fmaf(m, ai0 + ai1, (float)ig.x);                          \
    float gf = fmaf(m, af0 + af1, (float)fo.x);                          \
    float gg = fmaf(m, ag0 + ag1, (float)ig.y);                          \
    float go = fmaf(m, ao0 + ao1, (float)fo.y);                          \
    float iv = fast_sig(gi), fv = fast_sig(gf);                          \
    float gv = fast_tanh(gg), ov = fast_sig(go);                         \
    c = fmaf(fv, m * c, iv * gv);                                        \
    h = ov * fast_tanh(c);                                               \
    float hx = __shfl_xor(h, 1);                                         \
    pk = h2bits(__builtin_amdgcn_cvt_pkrtz(h, hx));                      \
    if ((lane & 33) == 0)                                                \
      Y16[((size_t)(TT)*BA + row)*16 + (u >> 1)] = pk;                   \
  }

  for (int t = 0; t < Tn; t += 4) {
    LSTM_PHASE(t + 0, q0)
    LSTM_PHASE(t + 1, q1)
    LSTM_PHASE(t + 2, q2)
    LSTM_PHASE(t + 3, q3)
  }
#undef LSTM_PHASE
}

// ---------------------------------------------------------------------------
// Heads: per row, 27 logits (3 heads x 9), log-softmax, entropy, gather,
// product of chosen log-probs. One thread per row; Y (fp16 pairs) read
// directly from global (single use - no LDS staging).
// ---------------------------------------------------------------------------
__global__ __launch_bounds__(256) void head_kernel(
    const unsigned* __restrict__ Y16, const float* __restrict__ Wh,
    const float* __restrict__ bh, const int* __restrict__ actions,
    float* __restrict__ out)
{
  __shared__ __align__(16) float whs[27*32];
  __shared__ float bhs[32];
  const int tid = threadIdx.x;
  const int R0 = blockIdx.x * 256;
  for (int i = tid; i < 27*32; i += 256) whs[i] = Wh[i];
  if (tid < 27) bhs[tid] = bh[tid];
  const int row = R0 + tid;
  float yv[32];
#pragma unroll
  for (int i4 = 0; i4 < 4; ++i4) {
    uint4 yw = *(const uint4*)&Y16[(size_t)row*16 + i4*4];
    pk16x2 p0 = bits2h(yw.x), p1 = bits2h(yw.y), p2 = bits2h(yw.z), p3 = bits2h(yw.w);
    yv[i4*8+0] = (float)p0.x; yv[i4*8+1] = (float)p0.y;
    yv[i4*8+2] = (float)p1.x; yv[i4*8+3] = (float)p1.y;
    yv[i4*8+4] = (float)p2.x; yv[i4*8+5] = (float)p2.y;
    yv[i4*8+6] = (float)p3.x; yv[i4*8+7] = (float)p3.y;
  }
  __syncthreads();
  float l[27];
#pragma unroll
  for (int m = 0; m < 27; ++m) {
    float a = bhs[m];
#pragma unroll
    for (int k4 = 0; k4 < 8; ++k4) {
      float4 w4 = *(const float4*)&whs[m*32 + k4*4];   // uniform -> broadcast
      a = fmaf(yv[k4*4+0], w4.x, a);
      a = fmaf(yv[k4*4+1], w4.y, a);
      a = fmaf(yv[k4*4+2], w4.z, a);
      a = fmaf(yv[k4*4+3], w4.w, a);
    }
    l[m] = a;
  }
  float logprob = 1.0f;
#pragma unroll
  for (int kk = 0; kk < 3; ++kk) {
    float mx = l[kk*9];
#pragma unroll
    for (int n = 1; n < 9; ++n) mx = fmaxf(mx, l[kk*9+n]);
    float s = 0.f;
#pragma unroll
    for (int n = 0; n < 9; ++n) s += __expf(l[kk*9+n] - mx);
    float lse = mx + __logf(s);
    float ent = 0.f;
#pragma unroll
    for (int n = 0; n < 9; ++n) {
      float lp = l[kk*9+n] - lse;
      ent -= __expf(lp) * lp;
    }
    int a = actions[row*3 + kk];
    float alp = 0.f;
#pragma unroll
    for (int n = 0; n < 9; ++n) alp = (a == n) ? (l[kk*9+n] - lse) : alp;
    logprob *= alp;
    out[row*3 + kk] = (float)a;          // actions echoed as float
    out[OUT_ENT + row*3 + kk] = ent;
  }
  out[OUT_LP + row] = logprob;
}

extern "C" void kernel_launch(void* const* d_in, const int* in_sizes, int n_in,
                              void* d_out, int out_size, void* d_ws, size_t ws_size,
                              hipStream_t stream)
{
  const float* x       = (const float*)d_in[0];
  const int*   done    = (const int*)  d_in[1];
  const int*   actions = (const int*)  d_in[2];
  const float* W1  = (const float*)d_in[3];
  const float* b1  = (const float*)d_in[4];
  const float* W2  = (const float*)d_in[5];
  const float* b2  = (const float*)d_in[6];
  const float* W3  = (const float*)d_in[7];
  const float* b3  = (const float*)d_in[8];
  const float* Wih = (const float*)d_in[9];
  const float* Whh = (const float*)d_in[10];
  const float* bih = (const float*)d_in[11];
  const float* bhh = (const float*)d_in[12];
  const float* Wh  = (const float*)d_in[13];
  const float* bh  = (const float*)d_in[14];
  const float* h0  = (const float*)d_in[15];
  const float* c0  = (const float*)d_in[16];
  float* out = (float*)d_out;

  uint2* G1q = (uint2*)d_ws;                         // TBA*32 uint2 = 16.8 MB
  unsigned* Y16 = (unsigned*)(G1q + (size_t)TBA*32); // TBA*16 uints =  4.2 MB
  _Float16* W16 = (_Float16*)(Y16 + (size_t)TBA*16); // 128 KB

  cvtw_kernel<<<W16_TOT/256, 256, 0, stream>>>(W1, W2, W3, Wih, W16);
  mlp_kernel<<<TBA/64, 256, 0, stream>>>(x, W16, b1, b2, b3, bih, bhh, G1q);
  lstm_kernel<<<BA, 64, 0, stream>>>(G1q, Whh, done, h0, c0, Y16);
  head_kernel<<<TBA/256, 256, 0, stream>>>(Y16, Wh, bh, actions, out);
}

// Round 9
// 198.877 us; speedup vs baseline: 1.2096x; 1.0091x over previous
//
#include <hip/hip_runtime.h>
#include <math.h>

namespace {
constexpr int Tn = 128, Bn = 16, An = 32, OBS = 256, Kh = 3, NACT = 9, HID = 32;
constexpr int TBA = Tn * Bn * An;   // 65536 rows through the MLP
constexpr int BA  = Bn * An;        // 512 LSTM sequences
constexpr int OUT_LP  = TBA * Kh;         // 196608: logprobs start
constexpr int OUT_ENT = TBA * Kh + TBA;   // 262144: entropies start

// fp16 weight pack offsets (elements)
constexpr int W1_OFF  = 0;       // 128x256
constexpr int W2_OFF  = 32768;   // 128x128
constexpr int W3_OFF  = 49152;   // 64x128
constexpr int WIH_OFF = 57344;   // 128x64
constexpr int W16_TOT = 65536;

typedef __fp16   pk16x2 __attribute__((ext_vector_type(2)));  // builtin-compatible
typedef _Float16 half8v __attribute__((ext_vector_type(8)));
typedef float    f32x4  __attribute__((ext_vector_type(4)));
}

__device__ __forceinline__ float fast_sig(float x) {
  return __builtin_amdgcn_rcpf(1.f + __expf(-x));
}
__device__ __forceinline__ float fast_tanh(float x) {   // 2*sig(2x)-1, saturates safely
  return fmaf(2.f, fast_sig(2.f * x), -1.f);
}
__device__ __forceinline__ unsigned h2bits(pk16x2 h) {
  return __builtin_bit_cast(unsigned, h);
}
__device__ __forceinline__ pk16x2 bits2h(unsigned u) {
  return __builtin_bit_cast(pk16x2, u);
}
__device__ __forceinline__ float dot2(pk16x2 a, pk16x2 b, float c) {
#if __has_builtin(__builtin_amdgcn_fdot2)
  return __builtin_amdgcn_fdot2(a, b, c, false);
#else
  c = fmaf((float)a.x, (float)b.x, c);
  return fmaf((float)a.y, (float)b.y, c);
#endif
}
// swap adjacent lanes (xor 1) via DPP quad_perm(1,0,3,2): VALU, no DS pipe
__device__ __forceinline__ float dpp_swap1(float x) {
  return __uint_as_float((unsigned)__builtin_amdgcn_mov_dpp(
      (int)__float_as_uint(x), 0xB1, 0xF, 0xF, true));
}

// ---------------------------------------------------------------------------
// Weight pre-conversion: all four matrices fp32 -> fp16 once per call.
// ---------------------------------------------------------------------------
__global__ __launch_bounds__(256) void cvtw_kernel(
    const float* __restrict__ W1, const float* __restrict__ W2,
    const float* __restrict__ W3, const float* __restrict__ Wih,
    _Float16* __restrict__ w16)
{
  int i = blockIdx.x * 256 + threadIdx.x;       // 0..65535
  float v;
  if (i < W2_OFF)       v = W1[i];
  else if (i < W3_OFF)  v = W2[i - W2_OFF];
  else if (i < WIH_OFF) v = W3[i - W3_OFF];
  else                  v = Wih[i - WIH_OFF];
  w16[i] = (_Float16)v;
}

// ---------------------------------------------------------------------------
// Fused MLP trunk + LSTM input projection, f16 MFMA (fp32 accumulate):
//   z = tanh(tanh(x@W1'+b1)@W2'+b2)@W3'+b3 ; G1 = z@Wih' + bih + bhh
// G1 stored as uint2 per (row, unit): {pk(i,g), pk(f,o)}.
// ---------------------------------------------------------------------------
template<int ROWS, int WSTR>
__device__ __forceinline__ void stage_wh(const _Float16* __restrict__ Wg, int kofs,
                                         _Float16* __restrict__ wt, int tid)
{
#pragma unroll
  for (int it = 0; it < ROWS/32; ++it) {
    int idx = tid + it*256;
    int o = idx >> 3, g8 = idx & 7;
    *(half8v*)&wt[o*72 + g8*8] =
        *(const half8v*)&Wg[(size_t)o*WSTR + kofs + g8*8];
  }
}

template<int NOC, int XSTR>
__device__ __forceinline__ void mfma_slab(const _Float16* __restrict__ xsrc,
                                          const _Float16* __restrict__ wt,
                                          int rA, int ln, int quad, f32x4 acc[8])
{
#pragma unroll
  for (int kc = 0; kc < 2; ++kc) {
    half8v a = *(const half8v*)&xsrc[rA*XSTR + kc*32 + quad*8];
#pragma unroll
    for (int oc = 0; oc < NOC; ++oc) {
      half8v b = *(const half8v*)&wt[(oc*16 + ln)*72 + kc*32 + quad*8];
      acc[oc] = __builtin_amdgcn_mfma_f32_16x16x32_f16(a, b, acc[oc], 0, 0, 0);
    }
  }
}

__global__ __launch_bounds__(256) void mlp_kernel(
    const float* __restrict__ x, const _Float16* __restrict__ w16,
    const float* __restrict__ b1, const float* __restrict__ b2,
    const float* __restrict__ b3, const float* __restrict__ bih,
    const float* __restrict__ bhh, uint2* __restrict__ G1q)
{
  __shared__ __align__(16) _Float16 xs[64*72];    // x k-slab; reused for z
  __shared__ __align__(16) _Float16 wt[128*72];   // weight k-slab
  __shared__ __align__(16) _Float16 act[64*136];  // activations (reused in place)
  const _Float16* W1h  = w16 + W1_OFF;
  const _Float16* W2h  = w16 + W2_OFF;
  const _Float16* W3h  = w16 + W3_OFF;
  const _Float16* Wihh = w16 + WIH_OFF;
  const int tid  = threadIdx.x;
  const int w    = tid >> 6;
  const int lane = tid & 63;
  const int ln   = lane & 15;
  const int quad = lane >> 4;
  const int rA   = 16*w + ln;
  const int r0   = 16*w + quad*4;
  const int R0   = blockIdx.x * 64;
  f32x4 acc[8];

  // ---- layer 1: 256 -> 128, tanh (4 k-slabs of 64) ----
#pragma unroll
  for (int oc = 0; oc < 8; ++oc) acc[oc] = (f32x4)0.f;
  for (int kt = 0; kt < 4; ++kt) {
#pragma unroll
    for (int it = 0; it < 2; ++it) {           // stage x slab [64][64] -> fp16
      int idx = tid + it*256;
      int r = idx >> 3, g8 = idx & 7;
      const float* xp = &x[(size_t)(R0 + r)*OBS + kt*64 + g8*8];
      float4 v0 = *(const float4*)xp;
      float4 v1 = *(const float4*)(xp + 4);
      half8v hv = { (_Float16)v0.x, (_Float16)v0.y, (_Float16)v0.z, (_Float16)v0.w,
                    (_Float16)v1.x, (_Float16)v1.y, (_Float16)v1.z, (_Float16)v1.w };
      *(half8v*)&xs[r*72 + g8*8] = hv;
    }
    stage_wh<128, 256>(W1h, kt*64, wt, tid);
    __syncthreads();
    mfma_slab<8, 72>(xs, wt, rA, ln, quad, acc);
    __syncthreads();
  }
#pragma unroll
  for (int oc = 0; oc < 8; ++oc) {
    int o = oc*16 + ln;
    float bv = b1[o];
#pragma unroll
    for (int r = 0; r < 4; ++r)
      act[(r0 + r)*136 + o] = (_Float16)fast_tanh(acc[oc][r] + bv);
  }

  // ---- layer 2: 128 -> 128, tanh ----
#pragma unroll
  for (int oc = 0; oc < 8; ++oc) acc[oc] = (f32x4)0.f;
  for (int kt = 0; kt < 2; ++kt) {
    stage_wh<128, 128>(W2h, kt*64, wt, tid);
    __syncthreads();                            // publishes act writes + wt
    mfma_slab<8, 136>(act + kt*64, wt, rA, ln, quad, acc);
    __syncthreads();
  }
#pragma unroll
  for (int oc = 0; oc < 8; ++oc) {
    int o = oc*16 + ln;
    float bv = b2[o];
#pragma unroll
    for (int r = 0; r < 4; ++r)
      act[(r0 + r)*136 + o] = (_Float16)fast_tanh(acc[oc][r] + bv);
  }

  // ---- layer 3: 128 -> 64, linear -> z into xs buffer ----
#pragma unroll
  for (int oc = 0; oc < 4; ++oc) acc[oc] = (f32x4)0.f;
  for (int kt = 0; kt < 2; ++kt) {
    stage_wh<64, 128>(W3h, kt*64, wt, tid);
    __syncthreads();
    mfma_slab<4, 136>(act + kt*64, wt, rA, ln, quad, acc);
    __syncthreads();
  }
#pragma unroll
  for (int oc = 0; oc < 4; ++oc) {
    int o = oc*16 + ln;
    float bv = b3[o];
#pragma unroll
    for (int r = 0; r < 4; ++r)
      xs[(r0 + r)*72 + o] = (_Float16)(acc[oc][r] + bv);
  }

  // ---- layer 4: z(64) -> 128 gate inputs, all 4 gates of unit u packed ----
#pragma unroll
  for (int oc = 0; oc < 8; ++oc) acc[oc] = (f32x4)0.f;
  stage_wh<128, 64>(Wihh, 0, wt, tid);
  __syncthreads();                              // publishes z writes + wt
  mfma_slab<8, 72>(xs, wt, rA, ln, quad, acc);
#pragma unroll
  for (int p = 0; p < 2; ++p) {
    int ui = p*16 + ln;
    float bi = bih[ui]      + bhh[ui];
    float bf = bih[ui + 32] + bhh[ui + 32];
    float bg = bih[ui + 64] + bhh[ui + 64];
    float bo = bih[ui + 96] + bhh[ui + 96];
#pragma unroll
    for (int r = 0; r < 4; ++r) {
      int n = R0 + r0 + r;
      uint2 q;
      q.x = h2bits(__builtin_amdgcn_cvt_pkrtz(acc[p  ][r] + bi, acc[p+4][r] + bg));
      q.y = h2bits(__builtin_amdgcn_cvt_pkrtz(acc[p+2][r] + bf, acc[p+6][r] + bo));
      G1q[(size_t)n*32 + ui] = q;
    }
  }
}

// ---------------------------------------------------------------------------
// LSTM scan v7: 1 row per 64-lane wave, 512 blocks, ZERO DS-pipe ops in the
// recurrence. v6's residual ~700cyc/step stall was two LDS round-trips on
// the serial chain (md[t] read + shfl_xor(h,1) as ds_swizzle, ~120cyc each):
//  - done masks now live in two 64-bit SGPR masks built once via __ballot;
//    per-step mask extraction is scalar-pipe (s_lshr/s_cselect), latency-free.
//  - h-pair swap is a DPP mov (quad_perm 0xB1), VALU-speed.
// Lane computes all 4 gates of unit u=lane&31 (upper half duplicates).
// G1 loads: manual 4-phase pipeline with distinct registers (vmcnt(3) slack).
// ---------------------------------------------------------------------------
__global__ __launch_bounds__(64) void lstm_kernel(
    const uint2* __restrict__ G1q, const float* __restrict__ Whh,
    const int* __restrict__ done, const float* __restrict__ h0,
    const float* __restrict__ c0, unsigned* __restrict__ Y16)
{
  const int lane = threadIdx.x;        // 0..63
  const int u = lane & 31;
  const int row = blockIdx.x;          // 0..511
  const int b = row >> 5;

  pk16x2 wi[16], wf[16], wg[16], wo[16];   // Whh rows u, u+32, u+64, u+96
#pragma unroll
  for (int k4 = 0; k4 < 8; ++k4) {
    float4 a  = *(const float4*)&Whh[(u      )*HID + k4*4];
    float4 bq = *(const float4*)&Whh[(u + 32 )*HID + k4*4];
    float4 cq = *(const float4*)&Whh[(u + 64 )*HID + k4*4];
    float4 dq = *(const float4*)&Whh[(u + 96 )*HID + k4*4];
    wi[2*k4+0] = __builtin_amdgcn_cvt_pkrtz(a.x,  a.y);
    wi[2*k4+1] = __builtin_amdgcn_cvt_pkrtz(a.z,  a.w);
    wf[2*k4+0] = __builtin_amdgcn_cvt_pkrtz(bq.x, bq.y);
    wf[2*k4+1] = __builtin_amdgcn_cvt_pkrtz(bq.z, bq.w);
    wg[2*k4+0] = __builtin_amdgcn_cvt_pkrtz(cq.x, cq.y);
    wg[2*k4+1] = __builtin_amdgcn_cvt_pkrtz(cq.z, cq.w);
    wo[2*k4+0] = __builtin_amdgcn_cvt_pkrtz(dq.x, dq.y);
    wo[2*k4+1] = __builtin_amdgcn_cvt_pkrtz(dq.z, dq.w);
  }

  // done -> two 64-bit wave-uniform SGPR masks (bit t = done[t,b] != 0)
  unsigned long long dm0 = __ballot(done[lane*Bn + b] != 0);          // t = 0..63
  unsigned long long dm1 = __ballot(done[(lane + 64)*Bn + b] != 0);   // t = 64..127

  float c = c0[row*HID + u];
  float h = h0[row*HID + u];
  unsigned pk = h2bits(__builtin_amdgcn_cvt_pkrtz(h, dpp_swap1(h)));

  const uint2* gbase = G1q + (size_t)row*32 + u;
  const size_t gstride = (size_t)BA*32;          // uint2 per step
  uint2 q0 = gbase[0*gstride];
  uint2 q1 = gbase[1*gstride];
  uint2 q2 = gbase[2*gstride];
  uint2 q3 = gbase[3*gstride];

#define LSTM_PHASE(TT, Q)                                                \
  {                                                                      \
    uint2 cur = Q;                                                       \
    int tnx = (TT) + 4; tnx = (tnx < Tn) ? tnx : (Tn - 1);               \
    Q = gbase[(size_t)tnx * gstride];                                    \
    unsigned long long dbit = ((TT) < 64) ? (dm0 >> (TT))                \
                                          : (dm1 >> ((TT) - 64));        \
    float m = (dbit & 1ull) ? 0.f : 1.f;   /* scalar-pipe select */      \
    unsigned hp[16];                                                     \
    _Pragma("unroll") for (int k = 0; k < 16; ++k)                       \
      hp[k] = __builtin_amdgcn_readlane(pk, 2*k);                        \
    float ai0=0.f, ai1=0.f, af0=0.f, af1=0.f;                            \
    float ag0=0.f, ag1=0.f, ao0=0.f, ao1=0.f;                            \
    _Pragma("unroll") for (int k = 0; k < 16; k += 2) {                  \
      pk16x2 ha = bits2h(hp[k]), hb = bits2h(hp[k+1]);                   \
      ai0 = dot2(wi[k], ha, ai0); ai1 = dot2(wi[k+1], hb, ai1);          \
      af0 = dot2(wf[k], ha, af0); af1 = dot2(wf[k+1], hb, af1);          \
      ag0 = dot2(wg[k], ha, ag0); ag1 = dot2(wg[k+1], hb, ag1);          \
      ao0 = dot2(wo[k], ha, ao0); ao1 = dot2(wo[k+1], hb, ao1);          \
    }                                                                    \
    pk16x2 ig = bits2h(cur.x), fo = bits2h(cur.y);                       \
    float gi = fmaf(m, ai0 + ai1, (float)ig.x);                          \
    float gf = fmaf(m, af0 + af1, (float)fo.x);                          \
    float gg = fmaf(m, ag0 + ag1, (float)ig.y);                          \
    float go = fmaf(m, ao0 + ao1, (float)fo.y);                          \
    float iv = fast_sig(gi), fv = fast_sig(gf);                          \
    float gv = fast_tanh(gg), ov = fast_sig(go);                         \
    c = fmaf(fv, m * c, iv * gv);                                        \
    h = ov * fast_tanh(c);                                               \
    pk = h2bits(__builtin_amdgcn_cvt_pkrtz(h, dpp_swap1(h)));            \
    if ((lane & 33) == 0)                                                \
      Y16[((size_t)(TT)*BA + row)*16 + (u >> 1)] = pk;                   \
  }

  for (int t = 0; t < Tn; t += 4) {
    LSTM_PHASE(t + 0, q0)
    LSTM_PHASE(t + 1, q1)
    LSTM_PHASE(t + 2, q2)
    LSTM_PHASE(t + 3, q3)
  }
#undef LSTM_PHASE
}

// ---------------------------------------------------------------------------
// Heads: per row, 27 logits (3 heads x 9), log-softmax, entropy, gather,
// product of chosen log-probs. One thread per row; Y (fp16 pairs) read
// directly from global (single use - no LDS staging).
// ---------------------------------------------------------------------------
__global__ __launch_bounds__(256) void head_kernel(
    const unsigned* __restrict__ Y16, const float* __restrict__ Wh,
    const float* __restrict__ bh, const int* __restrict__ actions,
    float* __restrict__ out)
{
  __shared__ __align__(16) float whs[27*32];
  __shared__ float bhs[32];
  const int tid = threadIdx.x;
  const int R0 = blockIdx.x * 256;
  for (int i = tid; i < 27*32; i += 256) whs[i] = Wh[i];
  if (tid < 27) bhs[tid] = bh[tid];
  const int row = R0 + tid;
  float yv[32];
#pragma unroll
  for (int i4 = 0; i4 < 4; ++i4) {
    uint4 yw = *(const uint4*)&Y16[(size_t)row*16 + i4*4];
    pk16x2 p0 = bits2h(yw.x), p1 = bits2h(yw.y), p2 = bits2h(yw.z), p3 = bits2h(yw.w);
    yv[i4*8+0] = (float)p0.x; yv[i4*8+1] = (float)p0.y;
    yv[i4*8+2] = (float)p1.x; yv[i4*8+3] = (float)p1.y;
    yv[i4*8+4] = (float)p2.x; yv[i4*8+5] = (float)p2.y;
    yv[i4*8+6] = (float)p3.x; yv[i4*8+7] = (float)p3.y;
  }
  __syncthreads();
  float l[27];
#pragma unroll
  for (int m = 0; m < 27; ++m) {
    float a = bhs[m];
#pragma unroll
    for (int k4 = 0; k4 < 8; ++k4) {
      float4 w4 = *(const float4*)&whs[m*32 + k4*4];   // uniform -> broadcast
      a = fmaf(yv[k4*4+0], w4.x, a);
      a = fmaf(yv[k4*4+1], w4.y, a);
      a = fmaf(yv[k4*4+2], w4.z, a);
      a = fmaf(yv[k4*4+3], w4.w, a);
    }
    l[m] = a;
  }
  float logprob = 1.0f;
#pragma unroll
  for (int kk = 0; kk < 3; ++kk) {
    float mx = l[kk*9];
#pragma unroll
    for (int n = 1; n < 9; ++n) mx = fmaxf(mx, l[kk*9+n]);
    float s = 0.f;
#pragma unroll
    for (int n = 0; n < 9; ++n) s += __expf(l[kk*9+n] - mx);
    float lse = mx + __logf(s);
    float ent = 0.f;
#pragma unroll
    for (int n = 0; n < 9; ++n) {
      float lp = l[kk*9+n] - lse;
      ent -= __expf(lp) * lp;
    }
    int a = actions[row*3 + kk];
    float alp = 0.f;
#pragma unroll
    for (int n = 0; n < 9; ++n) alp = (a == n) ? (l[kk*9+n] - lse) : alp;
    logprob *= alp;
    out[row*3 + kk] = (float)a;          // actions echoed as float
    out[OUT_ENT + row*3 + kk] = ent;
  }
  out[OUT_LP + row] = logprob;
}

extern "C" void kernel_launch(void* const* d_in, const int* in_sizes, int n_in,
                              void* d_out, int out_size, void* d_ws, size_t ws_size,
                              hipStream_t stream)
{
  const float* x       = (const float*)d_in[0];
  const int*   done    = (const int*)  d_in[1];
  const int*   actions = (const int*)  d_in[2];
  const float* W1  = (const float*)d_in[3];
  const float* b1  = (const float*)d_in[4];
  const float* W2  = (const float*)d_in[5];
  const float* b2  = (const float*)d_in[6];
  const float* W3  = (const float*)d_in[7];
  const float* b3  = (const float*)d_in[8];
  const float* Wih = (const float*)d_in[9];
  const float* Whh = (const float*)d_in[10];
  const float* bih = (const float*)d_in[11];
  const float* bhh = (const float*)d_in[12];
  const float* Wh  = (const float*)d_in[13];
  const float* bh  = (const float*)d_in[14];
  const float* h0  = (const float*)d_in[15];
  const float* c0  = (const float*)d_in[16];
  float* out = (float*)d_out;

  uint2* G1q = (uint2*)d_ws;                         // TBA*32 uint2 = 16.8 MB
  unsigned* Y16 = (unsigned*)(G1q + (size_t)TBA*32); // TBA*16 uints =  4.2 MB
  _Float16* W16 = (_Float16*)(Y16 + (size_t)TBA*16); // 128 KB

  cvtw_kernel<<<W16_TOT/256, 256, 0, stream>>>(W1, W2, W3, Wih, W16);
  mlp_kernel<<<TBA/64, 256, 0, stream>>>(x, W16, b1, b2, b3, bih, bhh, G1q);
  lstm_kernel<<<BA, 64, 0, stream>>>(G1q, Whh, done, h0, c0, Y16);
  head_kernel<<<TBA/256, 256, 0, stream>>>(Y16, Wh, bh, actions, out);
}